// Round 1
// baseline (379.918 us; speedup 1.0000x reference)
//
#include <hip/hip_runtime.h>

#define HWD 256
#define HW2 (HWD * HWD)        // 65536 spatial positions per plane
#define NB 8                   // batch
#define NC 64                  // channels
#define PLANE4 (HW2 / 4)       // 16384 float4 per spatial plane

// ---------------------------------------------------------------------------
// Kernel 1: channel-wise L1 norms for both inputs.
// One thread = 4 consecutive spatial positions (float4), loops over 64
// channels at stride HW2. Coalesced 16B/lane loads.
// grid: NB * PLANE4 / 256 = 512 blocks
// ---------------------------------------------------------------------------
__global__ void norms_kernel(const float* __restrict__ x1,
                             const float* __restrict__ x2,
                             float* __restrict__ n1,
                             float* __restrict__ n2) {
    int t = blockIdx.x * blockDim.x + threadIdx.x;   // [0, NB*PLANE4)
    int b = t >> 14;                                  // / PLANE4
    int p = t & (PLANE4 - 1);

    const float4* x1v = (const float4*)(x1 + (size_t)b * NC * HW2) + p;
    const float4* x2v = (const float4*)(x2 + (size_t)b * NC * HW2) + p;

    float4 a1 = make_float4(0.f, 0.f, 0.f, 0.f);
    float4 a2 = make_float4(0.f, 0.f, 0.f, 0.f);

#pragma unroll 8
    for (int c = 0; c < NC; ++c) {
        float4 v1 = x1v[(size_t)c * PLANE4];
        float4 v2 = x2v[(size_t)c * PLANE4];
        a1.x += fabsf(v1.x); a1.y += fabsf(v1.y);
        a1.z += fabsf(v1.z); a1.w += fabsf(v1.w);
        a2.x += fabsf(v2.x); a2.y += fabsf(v2.y);
        a2.z += fabsf(v2.z); a2.w += fabsf(v2.w);
    }

    ((float4*)n1)[t] = a1;
    ((float4*)n2)[t] = a2;
}

// ---------------------------------------------------------------------------
// Kernel 2: 3x3 conv (zero pad, taps from w) + bias on n1,n2; emit
// r = c1 / (c1 + c2). Tiny working set (4 MiB in, 2 MiB out) -> L2/L3.
// grid: NB * HW2 / 256 = 2048 blocks
// ---------------------------------------------------------------------------
__global__ void conv_ratio_kernel(const float* __restrict__ n1,
                                  const float* __restrict__ n2,
                                  const float* __restrict__ w,
                                  const float* __restrict__ bias,
                                  float* __restrict__ r) {
    int t = blockIdx.x * blockDim.x + threadIdx.x;   // [0, NB*HW2)
    int b = t >> 16;
    int sp = t & (HW2 - 1);
    int y = sp >> 8;
    int x = sp & (HWD - 1);

    const float* p1 = n1 + (size_t)b * HW2;
    const float* p2 = n2 + (size_t)b * HW2;

    float s1 = 0.f, s2 = 0.f;
#pragma unroll
    for (int dy = -1; dy <= 1; ++dy) {
        int yy = y + dy;
        if (yy < 0 || yy >= HWD) continue;
#pragma unroll
        for (int dx = -1; dx <= 1; ++dx) {
            int xx = x + dx;
            if (xx < 0 || xx >= HWD) continue;
            float wv = w[(dy + 1) * 3 + (dx + 1)];
            int o = yy * HWD + xx;
            s1 += wv * p1[o];
            s2 += wv * p2[o];
        }
    }
    float bv = bias[0];
    float c1 = s1 + bv;
    float c2 = s2 + bv;
    r[t] = c1 / (c1 + c2);
}

// ---------------------------------------------------------------------------
// Kernel 3: out = x1 * r + x2 * (1 - r), r broadcast over channels.
// One thread = one float4. r plane (2 MiB/batch total) stays in L3.
// grid: NB*NC*PLANE4 / 256 = 32768 blocks
// ---------------------------------------------------------------------------
__global__ void blend_kernel(const float* __restrict__ x1,
                             const float* __restrict__ x2,
                             const float* __restrict__ r,
                             float* __restrict__ out) {
    size_t t = (size_t)blockIdx.x * blockDim.x + threadIdx.x; // float4 index
    int sp4 = (int)(t & (PLANE4 - 1));
    int plane = (int)(t >> 14);       // b*NC + c
    int b = plane >> 6;               // / NC

    float4 v1 = ((const float4*)x1)[t];
    float4 v2 = ((const float4*)x2)[t];
    float4 rv = ((const float4*)r)[(size_t)b * PLANE4 + sp4];

    float4 o;
    o.x = v1.x * rv.x + v2.x * (1.f - rv.x);
    o.y = v1.y * rv.y + v2.y * (1.f - rv.y);
    o.z = v1.z * rv.z + v2.z * (1.f - rv.z);
    o.w = v1.w * rv.w + v2.w * (1.f - rv.w);

    ((float4*)out)[t] = o;
}

extern "C" void kernel_launch(void* const* d_in, const int* in_sizes, int n_in,
                              void* d_out, int out_size, void* d_ws, size_t ws_size,
                              hipStream_t stream) {
    const float* x1 = (const float*)d_in[0];
    const float* x2 = (const float*)d_in[1];
    const float* w  = (const float*)d_in[2];
    const float* bv = (const float*)d_in[3];
    float* out = (float*)d_out;

    // workspace layout: n1 | n2 | r, each NB*HW2 floats (2 MiB)
    float* n1 = (float*)d_ws;
    float* n2 = n1 + (size_t)NB * HW2;
    float* r  = n2 + (size_t)NB * HW2;

    const int block = 256;

    norms_kernel<<<NB * PLANE4 / block, block, 0, stream>>>(x1, x2, n1, n2);
    conv_ratio_kernel<<<NB * HW2 / block, block, 0, stream>>>(n1, n2, w, bv, r);
    blend_kernel<<<(size_t)NB * NC * PLANE4 / block, block, 0, stream>>>(x1, x2, r, out);
}

// Round 3
// 360.876 us; speedup vs baseline: 1.0528x; 1.0528x over previous
//
#include <hip/hip_runtime.h>

#define HWD 256
#define HW2 (HWD * HWD)        // 65536 spatial positions per plane
#define NB 8                   // batch
#define NC 64                  // channels
#define PLANE4 (HW2 / 4)       // 16384 float4 per spatial plane

typedef float floatx4 __attribute__((ext_vector_type(4)));

// ---------------------------------------------------------------------------
// Kernel 1: channel-wise L1 norms for both inputs.
// Block = 256 threads = 64 spatial float4 positions x 4 waves, each wave owns
// 16 channels. LDS reduction across the 4 waves at the end.
// grid: NB * PLANE4/64 = 2048 blocks  -> 8 blocks/CU, 32 waves/CU (full occ).
// Each thread issues 32 independent float4 loads (MLP).
// ---------------------------------------------------------------------------
__global__ void norms_kernel(const float* __restrict__ x1,
                             const float* __restrict__ x2,
                             float* __restrict__ n1,
                             float* __restrict__ n2) {
    const int s = threadIdx.x & 63;        // spatial float4 within tile
    const int g = threadIdx.x >> 6;        // wave id = channel group (0..3)
    const int blk = blockIdx.x;            // [0, NB*256)
    const int b = blk >> 8;                // batch
    const int p = ((blk & 255) << 6) + s;  // float4 index within plane

    const size_t base = (size_t)b * NC * PLANE4 + (size_t)g * 16 * PLANE4 + p;
    const float4* x1v = (const float4*)x1 + base;
    const float4* x2v = (const float4*)x2 + base;

    float4 a1 = make_float4(0.f, 0.f, 0.f, 0.f);
    float4 a2 = make_float4(0.f, 0.f, 0.f, 0.f);

#pragma unroll
    for (int c = 0; c < 16; ++c) {
        float4 v1 = x1v[(size_t)c * PLANE4];
        float4 v2 = x2v[(size_t)c * PLANE4];
        a1.x += fabsf(v1.x); a1.y += fabsf(v1.y);
        a1.z += fabsf(v1.z); a1.w += fabsf(v1.w);
        a2.x += fabsf(v2.x); a2.y += fabsf(v2.y);
        a2.z += fabsf(v2.z); a2.w += fabsf(v2.w);
    }

    __shared__ float4 l1[4][64];
    __shared__ float4 l2[4][64];
    l1[g][s] = a1;
    l2[g][s] = a2;
    __syncthreads();

    // wave 0 reduces n1, wave 1 reduces n2
    const size_t oidx = (size_t)b * PLANE4 + p;
    if (g == 0) {
        float4 r0 = l1[0][s], r1 = l1[1][s], r2 = l1[2][s], r3 = l1[3][s];
        float4 o;
        o.x = (r0.x + r1.x) + (r2.x + r3.x);
        o.y = (r0.y + r1.y) + (r2.y + r3.y);
        o.z = (r0.z + r1.z) + (r2.z + r3.z);
        o.w = (r0.w + r1.w) + (r2.w + r3.w);
        ((float4*)n1)[oidx] = o;
    } else if (g == 1) {
        float4 r0 = l2[0][s], r1 = l2[1][s], r2 = l2[2][s], r3 = l2[3][s];
        float4 o;
        o.x = (r0.x + r1.x) + (r2.x + r3.x);
        o.y = (r0.y + r1.y) + (r2.y + r3.y);
        o.z = (r0.z + r1.z) + (r2.z + r3.z);
        o.w = (r0.w + r1.w) + (r2.w + r3.w);
        ((float4*)n2)[oidx] = o;
    }
}

// ---------------------------------------------------------------------------
// Kernel 2: 3x3 conv (zero pad, taps from w) + bias on n1,n2; emit
// r = c1 / (c1 + c2). Tiny working set (4 MiB in, 2 MiB out) -> L2/L3.
// grid: NB * HW2 / 256 = 2048 blocks
// ---------------------------------------------------------------------------
__global__ void conv_ratio_kernel(const float* __restrict__ n1,
                                  const float* __restrict__ n2,
                                  const float* __restrict__ w,
                                  const float* __restrict__ bias,
                                  float* __restrict__ r) {
    int t = blockIdx.x * blockDim.x + threadIdx.x;   // [0, NB*HW2)
    int b = t >> 16;
    int sp = t & (HW2 - 1);
    int y = sp >> 8;
    int x = sp & (HWD - 1);

    const float* p1 = n1 + (size_t)b * HW2;
    const float* p2 = n2 + (size_t)b * HW2;

    float s1 = 0.f, s2 = 0.f;
#pragma unroll
    for (int dy = -1; dy <= 1; ++dy) {
        int yy = y + dy;
        if (yy < 0 || yy >= HWD) continue;
#pragma unroll
        for (int dx = -1; dx <= 1; ++dx) {
            int xx = x + dx;
            if (xx < 0 || xx >= HWD) continue;
            float wv = w[(dy + 1) * 3 + (dx + 1)];
            int o = yy * HWD + xx;
            s1 += wv * p1[o];
            s2 += wv * p2[o];
        }
    }
    float bv = bias[0];
    float c1 = s1 + bv;
    float c2 = s2 + bv;
    r[t] = c1 / (c1 + c2);
}

// ---------------------------------------------------------------------------
// Kernel 3: out = x1 * r + x2 * (1 - r), r broadcast over channels.
// One thread = one float4 spatial position x 8 channels (r loaded once,
// reused). Non-temporal stores keep the output stream out of L3 so x1/x2
// stay resident for re-read.
// grid: NB * (NC/8) * PLANE4 / 256 = 4096 blocks
// ---------------------------------------------------------------------------
__global__ void blend_kernel(const float* __restrict__ x1,
                             const float* __restrict__ x2,
                             const float* __restrict__ r,
                             float* __restrict__ out) {
    int t = blockIdx.x * blockDim.x + threadIdx.x;
    int p = t & (PLANE4 - 1);          // float4 within plane
    int cg = (t >> 14) & 7;            // channel group (8 channels each)
    int b = t >> 17;                   // batch

    float4 rv = ((const float4*)r)[(size_t)b * PLANE4 + p];
    float4 one_m;
    one_m.x = 1.f - rv.x; one_m.y = 1.f - rv.y;
    one_m.z = 1.f - rv.z; one_m.w = 1.f - rv.w;

    size_t base = ((size_t)b * NC + (size_t)cg * 8) * PLANE4 + p;
    const float4* x1v = (const float4*)x1 + base;
    const float4* x2v = (const float4*)x2 + base;
    floatx4* ov = (floatx4*)out + base;

#pragma unroll
    for (int c = 0; c < 8; ++c) {
        float4 v1 = x1v[(size_t)c * PLANE4];
        float4 v2 = x2v[(size_t)c * PLANE4];
        floatx4 o;
        o.x = v1.x * rv.x + v2.x * one_m.x;
        o.y = v1.y * rv.y + v2.y * one_m.y;
        o.z = v1.z * rv.z + v2.z * one_m.z;
        o.w = v1.w * rv.w + v2.w * one_m.w;
        __builtin_nontemporal_store(o, ov + (size_t)c * PLANE4);
    }
}

extern "C" void kernel_launch(void* const* d_in, const int* in_sizes, int n_in,
                              void* d_out, int out_size, void* d_ws, size_t ws_size,
                              hipStream_t stream) {
    const float* x1 = (const float*)d_in[0];
    const float* x2 = (const float*)d_in[1];
    const float* w  = (const float*)d_in[2];
    const float* bv = (const float*)d_in[3];
    float* out = (float*)d_out;

    // workspace layout: n1 | n2 | r, each NB*HW2 floats (2 MiB)
    float* n1 = (float*)d_ws;
    float* n2 = n1 + (size_t)NB * HW2;
    float* r  = n2 + (size_t)NB * HW2;

    const int block = 256;

    norms_kernel<<<NB * (PLANE4 / 64), block, 0, stream>>>(x1, x2, n1, n2);
    conv_ratio_kernel<<<NB * HW2 / block, block, 0, stream>>>(n1, n2, w, bv, r);
    blend_kernel<<<NB * (NC / 8) * PLANE4 / block, block, 0, stream>>>(x1, x2, r, out);
}